// Round 11
// baseline (340.063 us; speedup 1.0000x reference)
//
#include <hip/hip_runtime.h>
#include <math.h>

#define PI_F 3.14159265358979323846f

#define BATCH 4
#define CIN 256
#define CR 32
#define H0 224
#define HW0 (224*224)      // 50176
#define H1 111
#define HW1 (111*111)      // 12321
#define HS 35
#define HWS (35*35)        // 1225

typedef short bf16x8 __attribute__((ext_vector_type(8)));
typedef float f32x4 __attribute__((ext_vector_type(4)));
typedef unsigned int u32x4 __attribute__((ext_vector_type(4)));

__device__ inline unsigned pack2(float a, float b) {
  unsigned ua = __builtin_bit_cast(unsigned, a);
  unsigned ub = __builtin_bit_cast(unsigned, b);
  return ((ua + 0x8000u) >> 16) | (((ub + 0x8000u) >> 16) << 16);
}

__device__ inline bf16x8 pack8(const float f[8]) {
  u32x4 u;
  u[0] = pack2(f[0], f[1]);
  u[1] = pack2(f[2], f[3]);
  u[2] = pack2(f[4], f[5]);
  u[3] = pack2(f[6], f[7]);
  return __builtin_bit_cast(bf16x8, u);
}

// ---------------- Kernel 0: prep Wcat = wb*w1 (32x256), bias_v = wb*b1 + bb
__global__ __launch_bounds__(256) void k_prep(
    const float* __restrict__ w1, const float* __restrict__ b1,
    const float* __restrict__ wb, const float* __restrict__ bb,
    float* __restrict__ Wcat, float* __restrict__ bias_v) {
  __shared__ float wbl[32 * 32];
  int t = threadIdx.x;
  for (int i = t; i < 1024; i += 256) wbl[i] = wb[i];
  __syncthreads();
  float col[32];
#pragma unroll
  for (int m = 0; m < 32; ++m) col[m] = w1[m * CIN + t];
#pragma unroll
  for (int o = 0; o < 32; ++o) {
    float s = 0.f;
#pragma unroll
    for (int m = 0; m < 32; ++m) s = fmaf(wbl[o * 32 + m], col[m], s);
    Wcat[o * CIN + t] = s;
  }
  if (t < 32) {
    float s = bb[t];
#pragma unroll
    for (int m = 0; m < 32; ++m) s = fmaf(wbl[t * 32 + m], b1[m], s);
    bias_v[t] = s;
  }
}

// ---------------- Kernel 1: 1x1 reduce conv via MFMA (swapped operands:
// D[row=px, col=co]); emits c0 AND v0 with float4 stores.
__global__ __launch_bounds__(256) void k_conv1x1(
    const float* __restrict__ x, const float* __restrict__ w1,
    const float* __restrict__ b1, const float* __restrict__ Wcat,
    const float* __restrict__ bias_v,
    float* __restrict__ c0, float* __restrict__ v0) {
  int tid = threadIdx.x, lane = tid & 63, wid = tid >> 6;
  int l15 = lane & 15, lg = lane >> 4;
  int pxg = blockIdx.x * 256 + wid * 64;
  int b = pxg / HW0, p0 = pxg % HW0;
  f32x4 acc[4][4];
#pragma unroll
  for (int ct = 0; ct < 4; ++ct)
#pragma unroll
    for (int pt = 0; pt < 4; ++pt)
#pragma unroll
      for (int r = 0; r < 4; ++r) acc[ct][pt][r] = 0.f;
  const float* xb = x + (size_t)b * CIN * HW0 + p0 + l15;
  for (int ks = 0; ks < 8; ++ks) {
    bf16x8 Bf[4];
#pragma unroll
    for (int pt = 0; pt < 4; ++pt) {
      const float* xp = xb + (size_t)(ks * 32 + lg * 8) * HW0 + pt * 16;
      float f[8];
#pragma unroll
      for (int j = 0; j < 8; ++j) f[j] = xp[(size_t)j * HW0];
      Bf[pt] = pack8(f);
    }
    bf16x8 A[4];
#pragma unroll
    for (int ct = 0; ct < 4; ++ct) {
      const float* base = (ct < 2)
          ? w1 + (ct * 16 + l15) * CIN
          : Wcat + ((ct - 2) * 16 + l15) * CIN;
      const float* wr = base + ks * 32 + lg * 8;
      float f[8];
      float4 a0 = *reinterpret_cast<const float4*>(wr);
      float4 a1 = *reinterpret_cast<const float4*>(wr + 4);
      f[0]=a0.x; f[1]=a0.y; f[2]=a0.z; f[3]=a0.w;
      f[4]=a1.x; f[5]=a1.y; f[6]=a1.z; f[7]=a1.w;
      A[ct] = pack8(f);
    }
#pragma unroll
    for (int ct = 0; ct < 4; ++ct)
#pragma unroll
      for (int pt = 0; pt < 4; ++pt)
        acc[ct][pt] = __builtin_amdgcn_mfma_f32_16x16x32_bf16(
            Bf[pt], A[ct], acc[ct][pt], 0, 0, 0);   // swapped: row=px, col=co
  }
#pragma unroll
  for (int ct = 0; ct < 4; ++ct) {
    int co = (ct & 1) * 16 + l15;
    float bias = (ct < 2) ? b1[co] : bias_v[co];
    float* dst = (ct < 2) ? c0 : v0;
    float* ob = dst + ((size_t)b * CR + co) * HW0 + p0;
#pragma unroll
    for (int pt = 0; pt < 4; ++pt) {
      int pxo = pt * 16 + lg * 4;
      float4 r4 = make_float4(acc[ct][pt][0] + bias, acc[ct][pt][1] + bias,
                              acc[ct][pt][2] + bias, acc[ct][pt][3] + bias);
      *reinterpret_cast<float4*>(ob + pxo) = r4;
    }
  }
}

// ---------------- Kernel 2: 3x3 stride2 pad0: c0 -> c1[4,32,111,111]
#define PPR 56
#define PAIRS_B (H1 * PPR)
#define PAIRS_T (BATCH * PAIRS_B)
#define C3_THREADS (PAIRS_T * 4)
__global__ __launch_bounds__(256) void k_conv3x3s2(
    const float* __restrict__ c0, const float* __restrict__ wsw,
    const float* __restrict__ bs, float* __restrict__ c1) {
  __shared__ float wl[288 * 32];
  int tid = threadIdx.x;
  for (int i = tid; i < 9216; i += 256) {
    int o = i & 31, r = i >> 5;
    wl[i] = wsw[o * 288 + r];
  }
  __syncthreads();
  int T = blockIdx.x * 256 + tid;
  if (T >= C3_THREADS) return;
  int og = T / PAIRS_T;
  int pair = T % PAIRS_T;
  int b = pair / PAIRS_B;
  int pr = pair % PAIRS_B;
  int y = pr / PPR, xp = pr % PPR;
  bool tail = (xp == PPR - 1);
  const float* ibase = c0 + (size_t)b * CR * HW0 + (2 * y) * H0 + 4 * xp;
  float acc0[8], acc1[8];
#pragma unroll
  for (int j = 0; j < 8; ++j) { acc0[j] = 0.f; acc1[j] = 0.f; }
  for (int ci = 0; ci < CR; ++ci) {
    float p[3][5];
#pragma unroll
    for (int ky = 0; ky < 3; ++ky) {
      const float* rp = ibase + (size_t)ci * HW0 + ky * H0;
      float4 v = *reinterpret_cast<const float4*>(rp);
      p[ky][0] = v.x; p[ky][1] = v.y; p[ky][2] = v.z; p[ky][3] = v.w;
      p[ky][4] = tail ? 0.f : rp[4];
    }
    const float* wbase = &wl[ci * 9 * 32 + og * 8];
#pragma unroll
    for (int k = 0; k < 9; ++k) {
      int ky = k / 3, kx = k % 3;
      float4 wa = *reinterpret_cast<const float4*>(wbase + k * 32);
      float4 wc = *reinterpret_cast<const float4*>(wbase + k * 32 + 4);
      float wv[8] = {wa.x, wa.y, wa.z, wa.w, wc.x, wc.y, wc.z, wc.w};
      float pa = p[ky][kx], pb = p[ky][kx + 2];
#pragma unroll
      for (int j = 0; j < 8; ++j) {
        acc0[j] = fmaf(pa, wv[j], acc0[j]);
        acc1[j] = fmaf(pb, wv[j], acc1[j]);
      }
    }
  }
  float* ob = c1 + (size_t)b * CR * HW1 + y * H1 + 2 * xp;
  int o0 = og * 8;
#pragma unroll
  for (int j = 0; j < 8; ++j) {
    float bias = bs[o0 + j];
    ob[(size_t)(o0 + j) * HW1] = acc0[j] + bias;
    if (!tail) ob[(size_t)(o0 + j) * HW1 + 1] = acc1[j] + bias;
  }
}

// ---------------- Kernel 4: fused maxpool(7x7 s3) + FFT2 + fftshift + mask
__global__ __launch_bounds__(512) void k_fft(
    const float* __restrict__ c1, float* __restrict__ hb,
    float* __restrict__ cph, float* __restrict__ sph) {
  __shared__ float p[HWS];
  __shared__ float Tr[HWS], Ti[HWS];
  __shared__ float twc[HS], tws[HS];
  int img = blockIdx.x;
  const float* cb = c1 + (size_t)img * HW1;
  for (int i = threadIdx.x; i < HWS; i += 512) {
    int y = i / HS, x = i % HS;
    const float* ip = cb + (3 * y) * H1 + 3 * x;
    float m = -INFINITY;
#pragma unroll
    for (int ky = 0; ky < 7; ++ky)
#pragma unroll
      for (int kx = 0; kx < 7; ++kx)
        m = fmaxf(m, ip[ky * H1 + kx]);
    p[i] = m;
  }
  if (threadIdx.x < HS) {
    float ang = -2.f * PI_F * (float)threadIdx.x / (float)HS;
    twc[threadIdx.x] = cosf(ang);
    tws[threadIdx.x] = sinf(ang);
  }
  __syncthreads();
  for (int i = threadIdx.x; i < HWS; i += 512) {
    int u = i / HS, xx = i % HS;
    float sr = 0.f, si = 0.f;
    int t = 0;
    for (int y = 0; y < HS; ++y) {
      float v = p[y * HS + xx];
      sr = fmaf(v, twc[t], sr);
      si = fmaf(v, tws[t], si);
      t += u; if (t >= HS) t -= HS;
    }
    Tr[i] = sr; Ti[i] = si;
  }
  __syncthreads();
  float* hp = hb + (size_t)img * HWS;
  float* cp = cph + (size_t)img * HWS;
  float* sp = sph + (size_t)img * HWS;
  for (int i = threadIdx.x; i < HWS; i += 512) {
    int oy = i / HS, ox = i % HS;
    int u = oy + 18; if (u >= HS) u -= HS;
    int v = ox + 18; if (v >= HS) v -= HS;
    float fr = 0.f, fi = 0.f;
    int t = 0;
    for (int xx = 0; xx < HS; ++xx) {
      float tr = Tr[u * HS + xx], ti = Ti[u * HS + xx];
      float c = twc[t], s = tws[t];
      fr += tr * c - ti * s;
      fi += tr * s + ti * c;
      t += v; if (t >= HS) t -= HS;
    }
    float mag = sqrtf(fr * fr + fi * fi);
    float ic = 1.f, is = 0.f;
    if (mag > 0.f) { ic = fr / mag; is = fi / mag; }
    int dy = oy - 17, dx = ox - 17;
    float m = (dy * dy + dx * dx > 4) ? 1.f : 0.f;
    hp[i] = mag * m;
    cp[i] = ic; sp[i] = is;
  }
}

// ---------------- Kernel 5: fused DCN block. TPP=32, 8 px/block.
__global__ __launch_bounds__(256) void k_dcn(
    const float* __restrict__ hin, float* __restrict__ hout,
    const float* __restrict__ woff, const float* __restrict__ boff,
    const float* __restrict__ wreg, const float* __restrict__ breg) {
  __shared__ float wo[18 * CR * 9];
  __shared__ float wr[CR * CR * 9];
  __shared__ float bo[18], br[CR];
  for (int i = threadIdx.x; i < 18 * CR * 9; i += 256) wo[i] = woff[i];
  for (int i = threadIdx.x; i < CR * CR * 9; i += 256) wr[i] = wreg[i];
  if (threadIdx.x < 18) bo[threadIdx.x] = boff[threadIdx.x];
  if (threadIdx.x < CR) br[threadIdx.x] = breg[threadIdx.x];
  __syncthreads();
  int pg = threadIdx.x >> 5;
  int sub = threadIdx.x & 31;
  int pid = blockIdx.x * 8 + pg;
  bool active = pid < BATCH * HWS;
  int b = pid / HWS, r = pid % HWS;
  int y = r / HS, x = r % HS;
  const float* ib = hin + (size_t)b * CR * HWS;
  float off[18];
#pragma unroll
  for (int j = 0; j < 18; ++j) off[j] = 0.f;
  if (active) {
    const float* ip = ib + (size_t)sub * HWS;
#pragma unroll
    for (int ky = 0; ky < 3; ++ky) {
      int yy = y + ky - 1;
      if (yy < 0 || yy > HS - 1) continue;
#pragma unroll
      for (int kx = 0; kx < 3; ++kx) {
        int xx = x + kx - 1;
        if (xx < 0 || xx > HS - 1) continue;
        float v = ip[yy * HS + xx];
#pragma unroll
        for (int j = 0; j < 18; ++j)
          off[j] = fmaf(v, wo[(j * CR + sub) * 9 + ky * 3 + kx], off[j]);
      }
    }
  }
#pragma unroll
  for (int d = 1; d < 32; d <<= 1)
#pragma unroll
    for (int j = 0; j < 18; ++j)
      off[j] += __shfl_xor(off[j], d);
#pragma unroll
  for (int j = 0; j < 18; ++j) off[j] += bo[j];
  float acc[CR];
#pragma unroll
  for (int o = 0; o < CR; ++o) acc[o] = 0.f;
  if (active) {
    const float* ip = ib + (size_t)sub * HWS;
#pragma unroll
    for (int k = 0; k < 9; ++k) {
      int ky = k / 3, kx = k % 3;
      float ysf = (float)(y + ky - 1) + off[2 * k];
      float xsf = (float)(x + kx - 1) + off[2 * k + 1];
      float y0 = floorf(ysf), x0 = floorf(xsf);
      float fy = ysf - y0, fx = xsf - x0;
      float y1 = y0 + 1.f, x1 = x0 + 1.f;
      bool vy0 = (y0 >= 0.f) && (y0 <= 34.f);
      bool vy1 = (y1 >= 0.f) && (y1 <= 34.f);
      bool vx0 = (x0 >= 0.f) && (x0 <= 34.f);
      bool vx1 = (x1 >= 0.f) && (x1 <= 34.f);
      int iy0 = (int)fminf(fmaxf(y0, 0.f), 34.f);
      int iy1 = (int)fminf(fmaxf(y1, 0.f), 34.f);
      int ix0 = (int)fminf(fmaxf(x0, 0.f), 34.f);
      int ix1 = (int)fminf(fmaxf(x1, 0.f), 34.f);
      float w00 = (vy0 && vx0) ? (1.f - fy) * (1.f - fx) : 0.f;
      float w01 = (vy0 && vx1) ? (1.f - fy) * fx : 0.f;
      float w10 = (vy1 && vx0) ? fy * (1.f - fx) : 0.f;
      float w11 = (vy1 && vx1) ? fy * fx : 0.f;
      float s = w00 * ip[iy0 * HS + ix0] + w01 * ip[iy0 * HS + ix1]
              + w10 * ip[iy1 * HS + ix0] + w11 * ip[iy1 * HS + ix1];
#pragma unroll
      for (int o = 0; o < CR; ++o)
        acc[o] = fmaf(s, wr[(o * CR + sub) * 9 + k], acc[o]);
    }
  }
#pragma unroll
  for (int d = 1; d < 32; d <<= 1)
#pragma unroll
    for (int o = 0; o < CR; ++o)
      acc[o] += __shfl_xor(acc[o], d);
  if (active) {
    float* ob = hout + (size_t)b * CR * HWS + r;
    float v = acc[sub] + br[sub];
    ob[(size_t)sub * HWS] = fmaxf(v, 0.f);
  }
}

// ---------------- Kernel 6: iFFT2 with ifftshift folded in
__global__ __launch_bounds__(512) void k_ifft(
    const float* __restrict__ hb, const float* __restrict__ cph,
    const float* __restrict__ sph, float* __restrict__ rec) {
  __shared__ float Gr[HWS], Gi[HWS];
  __shared__ float Tr[HWS], Ti[HWS];
  __shared__ float twc[HS], tws[HS];
  int img = blockIdx.x;
  const float* hp = hb + (size_t)img * HWS;
  const float* cp = cph + (size_t)img * HWS;
  const float* sp = sph + (size_t)img * HWS;
  if (threadIdx.x < HS) {
    float ang = 2.f * PI_F * (float)threadIdx.x / (float)HS;
    twc[threadIdx.x] = cosf(ang);
    tws[threadIdx.x] = sinf(ang);
  }
  for (int i = threadIdx.x; i < HWS; i += 512) {
    int m = i / HS, n = i % HS;
    int sm = m + 17; if (sm >= HS) sm -= HS;
    int sn = n + 17; if (sn >= HS) sn -= HS;
    int si = sm * HS + sn;
    float h = hp[si];
    Gr[i] = h * cp[si];
    Gi[i] = h * sp[si];
  }
  __syncthreads();
  for (int i = threadIdx.x; i < HWS; i += 512) {
    int yy = i / HS, v = i % HS;
    float sr = 0.f, sii = 0.f;
    int t = 0;
    for (int u = 0; u < HS; ++u) {
      float gr = Gr[u * HS + v], gi = Gi[u * HS + v];
      float c = twc[t], s = tws[t];
      sr += gr * c - gi * s;
      sii += gr * s + gi * c;
      t += yy; if (t >= HS) t -= HS;
    }
    Tr[i] = sr; Ti[i] = sii;
  }
  __syncthreads();
  float* rp = rec + (size_t)img * HWS;
  const float inv = 1.f / (float)(HWS);
  for (int i = threadIdx.x; i < HWS; i += 512) {
    int yy = i / HS, xx = i % HS;
    float sr = 0.f;
    int t = 0;
    for (int v = 0; v < HS; ++v) {
      sr += Tr[yy * HS + v] * twc[t] - Ti[yy * HS + v] * tws[t];
      t += xx; if (t >= HS) t -= HS;
    }
    rp[i] = sr * inv;
  }
}

// ---------------- Kernel 7: gate via MFMA (swapped operands: row=px, col=co).
// Block = 64 px, 4 waves = 4 co-chunks; cooperative LDS B-build; float4 I/O.
__global__ __launch_bounds__(256) void k_final(
    const float* __restrict__ x, const float* __restrict__ v0buf,
    const float* __restrict__ rec,
    const float* __restrict__ w2, const float* __restrict__ b2,
    float* __restrict__ out) {
  __shared__ unsigned Bls[64 * 20];        // [px][stride 20 u32] (5 KB)
  int tid = threadIdx.x;
  int pxg = blockIdx.x * 64;               // 64 | HW0 -> no batch straddle
  int b = pxg / HW0, p0 = pxg % HW0;
  // ---- staging: thread (px = tid&63, half = tid>>6) packs 8 channels ----
  {
    int px = tid & 63, half = tid >> 6;
    int p = p0 + px;
    int h = p / H0, wc = p % H0;
    const float scale = (float)HS / (float)H0;
    float sy = ((float)h + 0.5f) * scale - 0.5f;
    float sx = ((float)wc + 0.5f) * scale - 0.5f;
    float y0f = floorf(sy), x0f = floorf(sx);
    float fy = sy - y0f, fx = sx - x0f;
    int y0 = max(0, min(HS - 1, (int)y0f));
    int y1 = max(0, min(HS - 1, (int)y0f + 1));
    int x0 = max(0, min(HS - 1, (int)x0f));
    int x1 = max(0, min(HS - 1, (int)x0f + 1));
    float w00 = (1.f - fy) * (1.f - fx), w01 = (1.f - fy) * fx;
    float w10 = fy * (1.f - fx), w11 = fy * fx;
    int i00 = y0 * HS + x0, i01 = y0 * HS + x1;
    int i10 = y1 * HS + x0, i11 = y1 * HS + x1;
    const float* rb = rec + ((size_t)b * CR + half * 8) * HWS;
    const float* vb = v0buf + ((size_t)b * CR + half * 8) * HW0 + p;
    float f[8];
#pragma unroll
    for (int j = 0; j < 8; ++j) {
      const float* rp = rb + (size_t)j * HWS;
      float u = w00 * rp[i00] + w01 * rp[i01] + w10 * rp[i10] + w11 * rp[i11];
      f[j] = vb[(size_t)j * HW0] + u;
    }
    u32x4 u4;
    u4[0] = pack2(f[0], f[1]);
    u4[1] = pack2(f[2], f[3]);
    u4[2] = pack2(f[4], f[5]);
    u4[3] = pack2(f[6], f[7]);
    *reinterpret_cast<u32x4*>(&Bls[px * 20 + half * 4]) = u4;
  }
  __syncthreads();
  // ---- MFMA phase: wave wid handles co chunk wid*64 ----
  int lane = tid & 63, wid = tid >> 6;
  int l15 = lane & 15, lg = lane >> 4;
  int ctb = wid * 64;
  bf16x8 Bf[4];
#pragma unroll
  for (int pt = 0; pt < 4; ++pt) {
    u32x4 u4 = *reinterpret_cast<const u32x4*>(&Bls[(pt * 16 + l15) * 20 + lg * 4]);
    Bf[pt] = __builtin_bit_cast(bf16x8, u4);
  }
  bf16x8 A[4];
#pragma unroll
  for (int ct = 0; ct < 4; ++ct) {
    const float* wr = w2 + (ctb + ct * 16 + l15) * CR + lg * 8;
    float f[8];
    float4 a0 = *reinterpret_cast<const float4*>(wr);
    float4 a1 = *reinterpret_cast<const float4*>(wr + 4);
    f[0]=a0.x; f[1]=a0.y; f[2]=a0.z; f[3]=a0.w;
    f[4]=a1.x; f[5]=a1.y; f[6]=a1.z; f[7]=a1.w;
    A[ct] = pack8(f);
  }
  f32x4 acc[4][4];
#pragma unroll
  for (int ct = 0; ct < 4; ++ct)
#pragma unroll
    for (int pt = 0; pt < 4; ++pt)
#pragma unroll
      for (int r = 0; r < 4; ++r) acc[ct][pt][r] = 0.f;
#pragma unroll
  for (int ct = 0; ct < 4; ++ct)
#pragma unroll
    for (int pt = 0; pt < 4; ++pt)
      acc[ct][pt] = __builtin_amdgcn_mfma_f32_16x16x32_bf16(
          Bf[pt], A[ct], acc[ct][pt], 0, 0, 0);   // swapped: row=px, col=co
#pragma unroll
  for (int ct = 0; ct < 4; ++ct) {
    int co = ctb + ct * 16 + l15;
    float bias = b2[co];
    const float* xb = x + ((size_t)b * CIN + co) * HW0 + p0;
    float* ob = out + ((size_t)b * CIN + co) * HW0 + p0;
#pragma unroll
    for (int pt = 0; pt < 4; ++pt) {
      int pxo = pt * 16 + lg * 4;
      float4 x4 = *reinterpret_cast<const float4*>(xb + pxo);
      float s0 = acc[ct][pt][0] + bias;
      float s1 = acc[ct][pt][1] + bias;
      float s2 = acc[ct][pt][2] + bias;
      float s3 = acc[ct][pt][3] + bias;
      float4 r4;
      r4.x = x4.x * __builtin_amdgcn_rcpf(1.f + __expf(-s0));
      r4.y = x4.y * __builtin_amdgcn_rcpf(1.f + __expf(-s1));
      r4.z = x4.z * __builtin_amdgcn_rcpf(1.f + __expf(-s2));
      r4.w = x4.w * __builtin_amdgcn_rcpf(1.f + __expf(-s3));
      *reinterpret_cast<float4*>(ob + pxo) = r4;
    }
  }
}

extern "C" void kernel_launch(void* const* d_in, const int* in_sizes, int n_in,
                              void* d_out, int out_size, void* d_ws, size_t ws_size,
                              hipStream_t stream) {
  const float* x    = (const float*)d_in[0];
  const float* w1   = (const float*)d_in[1];
  const float* b1   = (const float*)d_in[2];
  const float* wsw  = (const float*)d_in[3];
  const float* bs   = (const float*)d_in[4];
  const float* wb   = (const float*)d_in[5];
  const float* bb   = (const float*)d_in[6];
  const float* woff = (const float*)d_in[7];
  const float* boff = (const float*)d_in[8];
  const float* wreg = (const float*)d_in[9];
  const float* breg = (const float*)d_in[10];
  const float* w2   = (const float*)d_in[11];
  const float* b2   = (const float*)d_in[12];
  float* out = (float*)d_out;

  float* ws_f = (float*)d_ws;
  float* c0   = ws_f;
  float* v0   = c0 + (size_t)BATCH * CR * HW0;
  float* c1   = v0 + (size_t)BATCH * CR * HW0;
  float* hbA  = c1 + (size_t)BATCH * CR * HW1;
  float* hbB  = hbA + (size_t)BATCH * CR * HWS;
  float* cph  = hbB + (size_t)BATCH * CR * HWS;
  float* sph  = cph + (size_t)BATCH * CR * HWS;
  float* rec  = sph + (size_t)BATCH * CR * HWS;
  float* Wcat = rec + (size_t)BATCH * CR * HWS;
  float* bias_v = Wcat + 32 * CIN;

  k_prep<<<1, 256, 0, stream>>>(w1, b1, wb, bb, Wcat, bias_v);
  k_conv1x1<<<BATCH * HW0 / 256, 256, 0, stream>>>(x, w1, b1, Wcat, bias_v, c0, v0);
  k_conv3x3s2<<<(C3_THREADS + 255) / 256, 256, 0, stream>>>(c0, wsw, bs, c1);
  k_fft<<<BATCH * CR, 512, 0, stream>>>(c1, hbA, cph, sph);
  k_dcn<<<(BATCH * HWS + 7) / 8, 256, 0, stream>>>(hbA, hbB, woff, boff, wreg, breg);
  k_dcn<<<(BATCH * HWS + 7) / 8, 256, 0, stream>>>(hbB, hbA, woff + 5184, boff + 18, wreg + 9216, breg + 32);
  k_dcn<<<(BATCH * HWS + 7) / 8, 256, 0, stream>>>(hbA, hbB, woff + 2 * 5184, boff + 36, wreg + 2 * 9216, breg + 64);
  k_ifft<<<BATCH * CR, 512, 0, stream>>>(hbB, cph, sph, rec);
  dim3 gf(BATCH * HW0 / 64, 1);
  k_final<<<gf, 256, 0, stream>>>(x, v0, rec, w2, b2, out);
}

// Round 12
// 331.330 us; speedup vs baseline: 1.0264x; 1.0264x over previous
//
#include <hip/hip_runtime.h>
#include <math.h>

#define PI_F 3.14159265358979323846f

#define BATCH 4
#define CIN 256
#define CR 32
#define H0 224
#define HW0 (224*224)      // 50176
#define H1 111
#define HW1 (111*111)      // 12321
#define HS 35
#define HWS (35*35)        // 1225

typedef short bf16x8 __attribute__((ext_vector_type(8)));
typedef float f32x4 __attribute__((ext_vector_type(4)));
typedef unsigned int u32x4 __attribute__((ext_vector_type(4)));

__device__ inline unsigned pack2(float a, float b) {
  unsigned ua = __builtin_bit_cast(unsigned, a);
  unsigned ub = __builtin_bit_cast(unsigned, b);
  return ((ua + 0x8000u) >> 16) | (((ub + 0x8000u) >> 16) << 16);
}

__device__ inline bf16x8 pack8(const float f[8]) {
  u32x4 u;
  u[0] = pack2(f[0], f[1]);
  u[1] = pack2(f[2], f[3]);
  u[2] = pack2(f[4], f[5]);
  u[3] = pack2(f[6], f[7]);
  return __builtin_bit_cast(bf16x8, u);
}

// ---------------- Kernel 0: prep Wcat = wb*w1 (32x256), bias_v = wb*b1 + bb
__global__ __launch_bounds__(256) void k_prep(
    const float* __restrict__ w1, const float* __restrict__ b1,
    const float* __restrict__ wb, const float* __restrict__ bb,
    float* __restrict__ Wcat, float* __restrict__ bias_v) {
  __shared__ float wbl[32 * 32];
  int t = threadIdx.x;
  for (int i = t; i < 1024; i += 256) wbl[i] = wb[i];
  __syncthreads();
  float col[32];
#pragma unroll
  for (int m = 0; m < 32; ++m) col[m] = w1[m * CIN + t];
#pragma unroll
  for (int o = 0; o < 32; ++o) {
    float s = 0.f;
#pragma unroll
    for (int m = 0; m < 32; ++m) s = fmaf(wbl[o * 32 + m], col[m], s);
    Wcat[o * CIN + t] = s;
  }
  if (t < 32) {
    float s = bb[t];
#pragma unroll
    for (int m = 0; m < 32; ++m) s = fmaf(wbl[t * 32 + m], b1[m], s);
    bias_v[t] = s;
  }
}

// ---------------- Kernel 1: 1x1 reduce conv via MFMA (swapped operands:
// D[row=px, col=co]); emits c0 AND v0 with float4 stores.
__global__ __launch_bounds__(256) void k_conv1x1(
    const float* __restrict__ x, const float* __restrict__ w1,
    const float* __restrict__ b1, const float* __restrict__ Wcat,
    const float* __restrict__ bias_v,
    float* __restrict__ c0, float* __restrict__ v0) {
  int tid = threadIdx.x, lane = tid & 63, wid = tid >> 6;
  int l15 = lane & 15, lg = lane >> 4;
  int pxg = blockIdx.x * 256 + wid * 64;
  int b = pxg / HW0, p0 = pxg % HW0;
  f32x4 acc[4][4];
#pragma unroll
  for (int ct = 0; ct < 4; ++ct)
#pragma unroll
    for (int pt = 0; pt < 4; ++pt)
#pragma unroll
      for (int r = 0; r < 4; ++r) acc[ct][pt][r] = 0.f;
  const float* xb = x + (size_t)b * CIN * HW0 + p0 + l15;
  for (int ks = 0; ks < 8; ++ks) {
    bf16x8 Bf[4];
#pragma unroll
    for (int pt = 0; pt < 4; ++pt) {
      const float* xp = xb + (size_t)(ks * 32 + lg * 8) * HW0 + pt * 16;
      float f[8];
#pragma unroll
      for (int j = 0; j < 8; ++j) f[j] = xp[(size_t)j * HW0];
      Bf[pt] = pack8(f);
    }
    bf16x8 A[4];
#pragma unroll
    for (int ct = 0; ct < 4; ++ct) {
      const float* base = (ct < 2)
          ? w1 + (ct * 16 + l15) * CIN
          : Wcat + ((ct - 2) * 16 + l15) * CIN;
      const float* wr = base + ks * 32 + lg * 8;
      float f[8];
      float4 a0 = *reinterpret_cast<const float4*>(wr);
      float4 a1 = *reinterpret_cast<const float4*>(wr + 4);
      f[0]=a0.x; f[1]=a0.y; f[2]=a0.z; f[3]=a0.w;
      f[4]=a1.x; f[5]=a1.y; f[6]=a1.z; f[7]=a1.w;
      A[ct] = pack8(f);
    }
#pragma unroll
    for (int ct = 0; ct < 4; ++ct)
#pragma unroll
      for (int pt = 0; pt < 4; ++pt)
        acc[ct][pt] = __builtin_amdgcn_mfma_f32_16x16x32_bf16(
            Bf[pt], A[ct], acc[ct][pt], 0, 0, 0);   // swapped: row=px, col=co
  }
#pragma unroll
  for (int ct = 0; ct < 4; ++ct) {
    int co = (ct & 1) * 16 + l15;
    float bias = (ct < 2) ? b1[co] : bias_v[co];
    float* dst = (ct < 2) ? c0 : v0;
    float* ob = dst + ((size_t)b * CR + co) * HW0 + p0;
#pragma unroll
    for (int pt = 0; pt < 4; ++pt) {
      int pxo = pt * 16 + lg * 4;
      float4 r4 = make_float4(acc[ct][pt][0] + bias, acc[ct][pt][1] + bias,
                              acc[ct][pt][2] + bias, acc[ct][pt][3] + bias);
      *reinterpret_cast<float4*>(ob + pxo) = r4;
    }
  }
}

// ---------------- Kernel 2: 3x3 stride2 pad0: c0 -> c1[4,32,111,111]
#define PPR 56
#define PAIRS_B (H1 * PPR)
#define PAIRS_T (BATCH * PAIRS_B)
#define C3_THREADS (PAIRS_T * 4)
__global__ __launch_bounds__(256) void k_conv3x3s2(
    const float* __restrict__ c0, const float* __restrict__ wsw,
    const float* __restrict__ bs, float* __restrict__ c1) {
  __shared__ float wl[288 * 32];
  int tid = threadIdx.x;
  for (int i = tid; i < 9216; i += 256) {
    int o = i & 31, r = i >> 5;
    wl[i] = wsw[o * 288 + r];
  }
  __syncthreads();
  int T = blockIdx.x * 256 + tid;
  if (T >= C3_THREADS) return;
  int og = T / PAIRS_T;
  int pair = T % PAIRS_T;
  int b = pair / PAIRS_B;
  int pr = pair % PAIRS_B;
  int y = pr / PPR, xp = pr % PPR;
  bool tail = (xp == PPR - 1);
  const float* ibase = c0 + (size_t)b * CR * HW0 + (2 * y) * H0 + 4 * xp;
  float acc0[8], acc1[8];
#pragma unroll
  for (int j = 0; j < 8; ++j) { acc0[j] = 0.f; acc1[j] = 0.f; }
  for (int ci = 0; ci < CR; ++ci) {
    float p[3][5];
#pragma unroll
    for (int ky = 0; ky < 3; ++ky) {
      const float* rp = ibase + (size_t)ci * HW0 + ky * H0;
      float4 v = *reinterpret_cast<const float4*>(rp);
      p[ky][0] = v.x; p[ky][1] = v.y; p[ky][2] = v.z; p[ky][3] = v.w;
      p[ky][4] = tail ? 0.f : rp[4];
    }
    const float* wbase = &wl[ci * 9 * 32 + og * 8];
#pragma unroll
    for (int k = 0; k < 9; ++k) {
      int ky = k / 3, kx = k % 3;
      float4 wa = *reinterpret_cast<const float4*>(wbase + k * 32);
      float4 wc = *reinterpret_cast<const float4*>(wbase + k * 32 + 4);
      float wv[8] = {wa.x, wa.y, wa.z, wa.w, wc.x, wc.y, wc.z, wc.w};
      float pa = p[ky][kx], pb = p[ky][kx + 2];
#pragma unroll
      for (int j = 0; j < 8; ++j) {
        acc0[j] = fmaf(pa, wv[j], acc0[j]);
        acc1[j] = fmaf(pb, wv[j], acc1[j]);
      }
    }
  }
  float* ob = c1 + (size_t)b * CR * HW1 + y * H1 + 2 * xp;
  int o0 = og * 8;
#pragma unroll
  for (int j = 0; j < 8; ++j) {
    float bias = bs[o0 + j];
    ob[(size_t)(o0 + j) * HW1] = acc0[j] + bias;
    if (!tail) ob[(size_t)(o0 + j) * HW1 + 1] = acc1[j] + bias;
  }
}

// ---------------- Kernel 4: fused maxpool(7x7 s3) + FFT2 + fftshift + mask
__global__ __launch_bounds__(512) void k_fft(
    const float* __restrict__ c1, float* __restrict__ hb,
    float* __restrict__ cph, float* __restrict__ sph) {
  __shared__ float p[HWS];
  __shared__ float Tr[HWS], Ti[HWS];
  __shared__ float twc[HS], tws[HS];
  int img = blockIdx.x;
  const float* cb = c1 + (size_t)img * HW1;
  for (int i = threadIdx.x; i < HWS; i += 512) {
    int y = i / HS, x = i % HS;
    const float* ip = cb + (3 * y) * H1 + 3 * x;
    float m = -INFINITY;
#pragma unroll
    for (int ky = 0; ky < 7; ++ky)
#pragma unroll
      for (int kx = 0; kx < 7; ++kx)
        m = fmaxf(m, ip[ky * H1 + kx]);
    p[i] = m;
  }
  if (threadIdx.x < HS) {
    float ang = -2.f * PI_F * (float)threadIdx.x / (float)HS;
    twc[threadIdx.x] = cosf(ang);
    tws[threadIdx.x] = sinf(ang);
  }
  __syncthreads();
  for (int i = threadIdx.x; i < HWS; i += 512) {
    int u = i / HS, xx = i % HS;
    float sr = 0.f, si = 0.f;
    int t = 0;
    for (int y = 0; y < HS; ++y) {
      float v = p[y * HS + xx];
      sr = fmaf(v, twc[t], sr);
      si = fmaf(v, tws[t], si);
      t += u; if (t >= HS) t -= HS;
    }
    Tr[i] = sr; Ti[i] = si;
  }
  __syncthreads();
  float* hp = hb + (size_t)img * HWS;
  float* cp = cph + (size_t)img * HWS;
  float* sp = sph + (size_t)img * HWS;
  for (int i = threadIdx.x; i < HWS; i += 512) {
    int oy = i / HS, ox = i % HS;
    int u = oy + 18; if (u >= HS) u -= HS;
    int v = ox + 18; if (v >= HS) v -= HS;
    float fr = 0.f, fi = 0.f;
    int t = 0;
    for (int xx = 0; xx < HS; ++xx) {
      float tr = Tr[u * HS + xx], ti = Ti[u * HS + xx];
      float c = twc[t], s = tws[t];
      fr += tr * c - ti * s;
      fi += tr * s + ti * c;
      t += v; if (t >= HS) t -= HS;
    }
    float mag = sqrtf(fr * fr + fi * fi);
    float ic = 1.f, is = 0.f;
    if (mag > 0.f) { ic = fr / mag; is = fi / mag; }
    int dy = oy - 17, dx = ox - 17;
    float m = (dy * dy + dx * dx > 4) ? 1.f : 0.f;
    hp[i] = mag * m;
    cp[i] = ic; sp[i] = is;
  }
}

// ---------------- Kernel 5: fused DCN block. TPP=32, 8 px/block.
__global__ __launch_bounds__(256) void k_dcn(
    const float* __restrict__ hin, float* __restrict__ hout,
    const float* __restrict__ woff, const float* __restrict__ boff,
    const float* __restrict__ wreg, const float* __restrict__ breg) {
  __shared__ float wo[18 * CR * 9];
  __shared__ float wr[CR * CR * 9];
  __shared__ float bo[18], br[CR];
  for (int i = threadIdx.x; i < 18 * CR * 9; i += 256) wo[i] = woff[i];
  for (int i = threadIdx.x; i < CR * CR * 9; i += 256) wr[i] = wreg[i];
  if (threadIdx.x < 18) bo[threadIdx.x] = boff[threadIdx.x];
  if (threadIdx.x < CR) br[threadIdx.x] = breg[threadIdx.x];
  __syncthreads();
  int pg = threadIdx.x >> 5;
  int sub = threadIdx.x & 31;
  int pid = blockIdx.x * 8 + pg;
  bool active = pid < BATCH * HWS;
  int b = pid / HWS, r = pid % HWS;
  int y = r / HS, x = r % HS;
  const float* ib = hin + (size_t)b * CR * HWS;
  float off[18];
#pragma unroll
  for (int j = 0; j < 18; ++j) off[j] = 0.f;
  if (active) {
    const float* ip = ib + (size_t)sub * HWS;
#pragma unroll
    for (int ky = 0; ky < 3; ++ky) {
      int yy = y + ky - 1;
      if (yy < 0 || yy > HS - 1) continue;
#pragma unroll
      for (int kx = 0; kx < 3; ++kx) {
        int xx = x + kx - 1;
        if (xx < 0 || xx > HS - 1) continue;
        float v = ip[yy * HS + xx];
#pragma unroll
        for (int j = 0; j < 18; ++j)
          off[j] = fmaf(v, wo[(j * CR + sub) * 9 + ky * 3 + kx], off[j]);
      }
    }
  }
#pragma unroll
  for (int d = 1; d < 32; d <<= 1)
#pragma unroll
    for (int j = 0; j < 18; ++j)
      off[j] += __shfl_xor(off[j], d);
#pragma unroll
  for (int j = 0; j < 18; ++j) off[j] += bo[j];
  float acc[CR];
#pragma unroll
  for (int o = 0; o < CR; ++o) acc[o] = 0.f;
  if (active) {
    const float* ip = ib + (size_t)sub * HWS;
#pragma unroll
    for (int k = 0; k < 9; ++k) {
      int ky = k / 3, kx = k % 3;
      float ysf = (float)(y + ky - 1) + off[2 * k];
      float xsf = (float)(x + kx - 1) + off[2 * k + 1];
      float y0 = floorf(ysf), x0 = floorf(xsf);
      float fy = ysf - y0, fx = xsf - x0;
      float y1 = y0 + 1.f, x1 = x0 + 1.f;
      bool vy0 = (y0 >= 0.f) && (y0 <= 34.f);
      bool vy1 = (y1 >= 0.f) && (y1 <= 34.f);
      bool vx0 = (x0 >= 0.f) && (x0 <= 34.f);
      bool vx1 = (x1 >= 0.f) && (x1 <= 34.f);
      int iy0 = (int)fminf(fmaxf(y0, 0.f), 34.f);
      int iy1 = (int)fminf(fmaxf(y1, 0.f), 34.f);
      int ix0 = (int)fminf(fmaxf(x0, 0.f), 34.f);
      int ix1 = (int)fminf(fmaxf(x1, 0.f), 34.f);
      float w00 = (vy0 && vx0) ? (1.f - fy) * (1.f - fx) : 0.f;
      float w01 = (vy0 && vx1) ? (1.f - fy) * fx : 0.f;
      float w10 = (vy1 && vx0) ? fy * (1.f - fx) : 0.f;
      float w11 = (vy1 && vx1) ? fy * fx : 0.f;
      float s = w00 * ip[iy0 * HS + ix0] + w01 * ip[iy0 * HS + ix1]
              + w10 * ip[iy1 * HS + ix0] + w11 * ip[iy1 * HS + ix1];
#pragma unroll
      for (int o = 0; o < CR; ++o)
        acc[o] = fmaf(s, wr[(o * CR + sub) * 9 + k], acc[o]);
    }
  }
#pragma unroll
  for (int d = 1; d < 32; d <<= 1)
#pragma unroll
    for (int o = 0; o < CR; ++o)
      acc[o] += __shfl_xor(acc[o], d);
  if (active) {
    float* ob = hout + (size_t)b * CR * HWS + r;
    float v = acc[sub] + br[sub];
    ob[(size_t)sub * HWS] = fmaxf(v, 0.f);
  }
}

// ---------------- Kernel 6: iFFT2 with ifftshift folded in
__global__ __launch_bounds__(512) void k_ifft(
    const float* __restrict__ hb, const float* __restrict__ cph,
    const float* __restrict__ sph, float* __restrict__ rec) {
  __shared__ float Gr[HWS], Gi[HWS];
  __shared__ float Tr[HWS], Ti[HWS];
  __shared__ float twc[HS], tws[HS];
  int img = blockIdx.x;
  const float* hp = hb + (size_t)img * HWS;
  const float* cp = cph + (size_t)img * HWS;
  const float* sp = sph + (size_t)img * HWS;
  if (threadIdx.x < HS) {
    float ang = 2.f * PI_F * (float)threadIdx.x / (float)HS;
    twc[threadIdx.x] = cosf(ang);
    tws[threadIdx.x] = sinf(ang);
  }
  for (int i = threadIdx.x; i < HWS; i += 512) {
    int m = i / HS, n = i % HS;
    int sm = m + 17; if (sm >= HS) sm -= HS;
    int sn = n + 17; if (sn >= HS) sn -= HS;
    int si = sm * HS + sn;
    float h = hp[si];
    Gr[i] = h * cp[si];
    Gi[i] = h * sp[si];
  }
  __syncthreads();
  for (int i = threadIdx.x; i < HWS; i += 512) {
    int yy = i / HS, v = i % HS;
    float sr = 0.f, sii = 0.f;
    int t = 0;
    for (int u = 0; u < HS; ++u) {
      float gr = Gr[u * HS + v], gi = Gi[u * HS + v];
      float c = twc[t], s = tws[t];
      sr += gr * c - gi * s;
      sii += gr * s + gi * c;
      t += yy; if (t >= HS) t -= HS;
    }
    Tr[i] = sr; Ti[i] = sii;
  }
  __syncthreads();
  float* rp = rec + (size_t)img * HWS;
  const float inv = 1.f / (float)(HWS);
  for (int i = threadIdx.x; i < HWS; i += 512) {
    int yy = i / HS, xx = i % HS;
    float sr = 0.f;
    int t = 0;
    for (int v = 0; v < HS; ++v) {
      sr += Tr[yy * HS + v] * twc[t] - Ti[yy * HS + v] * tws[t];
      t += xx; if (t >= HS) t -= HS;
    }
    rp[i] = sr * inv;
  }
}

// ---------------- Kernel 7: gate via MFMA (row=px, col=co), LDS B-build,
// and EARLY x-prefetch: all 16 x float4 issued before staging so their
// latency hides under rec-gather + barrier + MFMA.
__global__ __launch_bounds__(256) void k_final(
    const float* __restrict__ x, const float* __restrict__ v0buf,
    const float* __restrict__ rec,
    const float* __restrict__ w2, const float* __restrict__ b2,
    float* __restrict__ out) {
  __shared__ unsigned Bls[64 * 20];        // [px][stride 20 u32] (5 KB)
  int tid = threadIdx.x;
  int pxg = blockIdx.x * 64;               // 64 | HW0 -> no batch straddle
  int b = pxg / HW0, p0 = pxg % HW0;
  int lane = tid & 63, wid = tid >> 6;
  int l15 = lane & 15, lg = lane >> 4;
  int ctb = wid * 64;
  // ---- EARLY x prefetch: 16 independent float4 loads, used only in epilogue
  float4 xpre[4][4];
#pragma unroll
  for (int ct = 0; ct < 4; ++ct) {
    int co = ctb + ct * 16 + l15;
    const float* xb = x + ((size_t)b * CIN + co) * HW0 + p0;
#pragma unroll
    for (int pt = 0; pt < 4; ++pt)
      xpre[ct][pt] = *reinterpret_cast<const float4*>(xb + pt * 16 + lg * 4);
  }
  // ---- staging: thread (px = tid&63, half = tid>>6) packs 8 channels ----
  {
    int px = tid & 63, half = tid >> 6;
    int p = p0 + px;
    int h = p / H0, wc = p % H0;
    const float scale = (float)HS / (float)H0;
    float sy = ((float)h + 0.5f) * scale - 0.5f;
    float sx = ((float)wc + 0.5f) * scale - 0.5f;
    float y0f = floorf(sy), x0f = floorf(sx);
    float fy = sy - y0f, fx = sx - x0f;
    int y0 = max(0, min(HS - 1, (int)y0f));
    int y1 = max(0, min(HS - 1, (int)y0f + 1));
    int x0 = max(0, min(HS - 1, (int)x0f));
    int x1 = max(0, min(HS - 1, (int)x0f + 1));
    float w00 = (1.f - fy) * (1.f - fx), w01 = (1.f - fy) * fx;
    float w10 = fy * (1.f - fx), w11 = fy * fx;
    int i00 = y0 * HS + x0, i01 = y0 * HS + x1;
    int i10 = y1 * HS + x0, i11 = y1 * HS + x1;
    const float* rb = rec + ((size_t)b * CR + half * 8) * HWS;
    const float* vb = v0buf + ((size_t)b * CR + half * 8) * HW0 + p;
    float f[8];
#pragma unroll
    for (int j = 0; j < 8; ++j) {
      const float* rp = rb + (size_t)j * HWS;
      float u = w00 * rp[i00] + w01 * rp[i01] + w10 * rp[i10] + w11 * rp[i11];
      f[j] = vb[(size_t)j * HW0] + u;
    }
    u32x4 u4;
    u4[0] = pack2(f[0], f[1]);
    u4[1] = pack2(f[2], f[3]);
    u4[2] = pack2(f[4], f[5]);
    u4[3] = pack2(f[6], f[7]);
    *reinterpret_cast<u32x4*>(&Bls[px * 20 + half * 4]) = u4;
  }
  __syncthreads();
  // ---- MFMA phase: wave wid handles co chunk wid*64 ----
  bf16x8 Bf[4];
#pragma unroll
  for (int pt = 0; pt < 4; ++pt) {
    u32x4 u4 = *reinterpret_cast<const u32x4*>(&Bls[(pt * 16 + l15) * 20 + lg * 4]);
    Bf[pt] = __builtin_bit_cast(bf16x8, u4);
  }
  bf16x8 A[4];
#pragma unroll
  for (int ct = 0; ct < 4; ++ct) {
    const float* wr = w2 + (ctb + ct * 16 + l15) * CR + lg * 8;
    float f[8];
    float4 a0 = *reinterpret_cast<const float4*>(wr);
    float4 a1 = *reinterpret_cast<const float4*>(wr + 4);
    f[0]=a0.x; f[1]=a0.y; f[2]=a0.z; f[3]=a0.w;
    f[4]=a1.x; f[5]=a1.y; f[6]=a1.z; f[7]=a1.w;
    A[ct] = pack8(f);
  }
  f32x4 acc[4][4];
#pragma unroll
  for (int ct = 0; ct < 4; ++ct)
#pragma unroll
    for (int pt = 0; pt < 4; ++pt)
#pragma unroll
      for (int r = 0; r < 4; ++r) acc[ct][pt][r] = 0.f;
#pragma unroll
  for (int ct = 0; ct < 4; ++ct)
#pragma unroll
    for (int pt = 0; pt < 4; ++pt)
      acc[ct][pt] = __builtin_amdgcn_mfma_f32_16x16x32_bf16(
          Bf[pt], A[ct], acc[ct][pt], 0, 0, 0);   // swapped: row=px, col=co
#pragma unroll
  for (int ct = 0; ct < 4; ++ct) {
    int co = ctb + ct * 16 + l15;
    float bias = b2[co];
    float* ob = out + ((size_t)b * CIN + co) * HW0 + p0;
#pragma unroll
    for (int pt = 0; pt < 4; ++pt) {
      int pxo = pt * 16 + lg * 4;
      float4 x4 = xpre[ct][pt];
      float s0 = acc[ct][pt][0] + bias;
      float s1 = acc[ct][pt][1] + bias;
      float s2 = acc[ct][pt][2] + bias;
      float s3 = acc[ct][pt][3] + bias;
      float4 r4;
      r4.x = x4.x * __builtin_amdgcn_rcpf(1.f + __expf(-s0));
      r4.y = x4.y * __builtin_amdgcn_rcpf(1.f + __expf(-s1));
      r4.z = x4.z * __builtin_amdgcn_rcpf(1.f + __expf(-s2));
      r4.w = x4.w * __builtin_amdgcn_rcpf(1.f + __expf(-s3));
      *reinterpret_cast<float4*>(ob + pxo) = r4;
    }
  }
}

extern "C" void kernel_launch(void* const* d_in, const int* in_sizes, int n_in,
                              void* d_out, int out_size, void* d_ws, size_t ws_size,
                              hipStream_t stream) {
  const float* x    = (const float*)d_in[0];
  const float* w1   = (const float*)d_in[1];
  const float* b1   = (const float*)d_in[2];
  const float* wsw  = (const float*)d_in[3];
  const float* bs   = (const float*)d_in[4];
  const float* wb   = (const float*)d_in[5];
  const float* bb   = (const float*)d_in[6];
  const float* woff = (const float*)d_in[7];
  const float* boff = (const float*)d_in[8];
  const float* wreg = (const float*)d_in[9];
  const float* breg = (const float*)d_in[10];
  const float* w2   = (const float*)d_in[11];
  const float* b2   = (const float*)d_in[12];
  float* out = (float*)d_out;

  float* ws_f = (float*)d_ws;
  float* c0   = ws_f;
  float* v0   = c0 + (size_t)BATCH * CR * HW0;
  float* c1   = v0 + (size_t)BATCH * CR * HW0;
  float* hbA  = c1 + (size_t)BATCH * CR * HW1;
  float* hbB  = hbA + (size_t)BATCH * CR * HWS;
  float* cph  = hbB + (size_t)BATCH * CR * HWS;
  float* sph  = cph + (size_t)BATCH * CR * HWS;
  float* rec  = sph + (size_t)BATCH * CR * HWS;
  float* Wcat = rec + (size_t)BATCH * CR * HWS;
  float* bias_v = Wcat + 32 * CIN;

  k_prep<<<1, 256, 0, stream>>>(w1, b1, wb, bb, Wcat, bias_v);
  k_conv1x1<<<BATCH * HW0 / 256, 256, 0, stream>>>(x, w1, b1, Wcat, bias_v, c0, v0);
  k_conv3x3s2<<<(C3_THREADS + 255) / 256, 256, 0, stream>>>(c0, wsw, bs, c1);
  k_fft<<<BATCH * CR, 512, 0, stream>>>(c1, hbA, cph, sph);
  k_dcn<<<(BATCH * HWS + 7) / 8, 256, 0, stream>>>(hbA, hbB, woff, boff, wreg, breg);
  k_dcn<<<(BATCH * HWS + 7) / 8, 256, 0, stream>>>(hbB, hbA, woff + 5184, boff + 18, wreg + 9216, breg + 32);
  k_dcn<<<(BATCH * HWS + 7) / 8, 256, 0, stream>>>(hbA, hbB, woff + 2 * 5184, boff + 36, wreg + 2 * 9216, breg + 64);
  k_ifft<<<BATCH * CR, 512, 0, stream>>>(hbB, cph, sph, rec);
  dim3 gf(BATCH * HW0 / 64, 1);
  k_final<<<gf, 256, 0, stream>>>(x, v0, rec, w2, b2, out);
}